// Round 6
// baseline (219.043 us; speedup 1.0000x reference)
//
#include <hip/hip_runtime.h>
#include <hip/hip_bf16.h>
#include <cstdint>
#include <cstddef>

typedef __bf16 bf16;
typedef __attribute__((ext_vector_type(8))) __bf16 bf16x8;
typedef __attribute__((ext_vector_type(4))) float f32x4;

static_assert(sizeof(bf16x8) == 16, "bf16x8 must be 16B");

#define NTASK 34
#define BTOT 16384

__device__ __forceinline__ f32x4 mfma16(bf16x8 a, bf16x8 b, f32x4 c) {
  return __builtin_amdgcn_mfma_f32_16x16x32_bf16(a, b, c, 0, 0, 0);
}

__device__ __forceinline__ void gload_lds16(const void* g, void* l) {
  __builtin_amdgcn_global_load_lds((__attribute__((address_space(1))) void*)g,
                                   (__attribute__((address_space(3))) void*)l,
                                   16, 0, 0);
}

__device__ __forceinline__ unsigned pack2(float lo, float hi) {
  union { __bf16 h[2]; unsigned u; } v;
  v.h[0] = (__bf16)lo; v.h[1] = (__bf16)hi;
  return v.u;
}

// ---------------- prep kernels ----------------

// All weights -> bf16 MFMA-fragment chunks, per-task stream of 16 x 8KB.
// chunk c of task n at dst[(n*16+c)*4096 ...]; elem (ct*64+l)*8+j holds
// W[n][k = ks*32 + (l>>4)*8 + j][col = ct*16 + (l&15)], ks relative to layer.
__global__ void prep_w_all(const float* __restrict__ W1, const float* __restrict__ W2,
                           const float* __restrict__ W3, bf16* __restrict__ dst) {
  int idx = blockIdx.x * 256 + threadIdx.x;   // 34*16*512 = 278528 exact
  int n = idx >> 13;
  int r = idx & 8191;
  int c = r >> 9;           // chunk 0..15
  int r2 = r & 511;
  int ct = r2 >> 6;
  int l = r2 & 63;
  int col = ct * 16 + (l & 15);
  int krel = (l >> 4) << 3;
  const float* s;
  if (c < 8)       s = W1 + ((size_t)n * 256 + c * 32 + krel) * 128 + col;
  else if (c < 12) s = W2 + ((size_t)n * 128 + (c - 8) * 32 + krel) * 128 + col;
  else             s = W3 + ((size_t)n * 128 + (c - 12) * 32 + krel) * 128 + col;
  bf16x8 v;
#pragma unroll
  for (int j = 0; j < 8; ++j) v[j] = (bf16)s[(size_t)j * 128];
  *(bf16x8*)(dst + ((size_t)n * 16 + c) * 4096 + (ct * 64 + l) * 8) = v;
}

__global__ void prep_langn(const float* __restrict__ lang, float* __restrict__ out) {
  __shared__ float red[2];
  int n = blockIdx.x;
  int t = threadIdx.x;                        // 128 threads
  float v = lang[(size_t)n * 128 + t];
  float ss = v * v;
#pragma unroll
  for (int m = 1; m < 64; m <<= 1) ss += __shfl_xor(ss, m);
  if ((t & 63) == 0) red[t >> 6] = ss;
  __syncthreads();
  float s = red[0] + red[1];
  float sc = 1.0f / fmaxf(sqrtf(s), 1e-8f);
  out[(size_t)n * 128 + t] = v * sc;
}

// ---------------- pass 1 ----------------
// grid: blk = n*64 + rg (task-major), 512 thr = 8 waves, 32 rows/wave (rt=2x16).
// W1 staged in LDS (64KB, 2 blocks/CU); W2/W3 frags read global->reg from L2.
// Swapped MFMA: T[hcol][batch] = W^T . x^T, lane&15 = batch (verified r4/r5).

__global__ void __launch_bounds__(512, 4)
pass1_kernel(const int* __restrict__ task_id,
             const float* __restrict__ b1, const float* __restrict__ b2,
             const float* __restrict__ b3,
             const bf16* __restrict__ wstream, const float* __restrict__ state,
             const float* __restrict__ langn,
             float* __restrict__ cs_t, float* __restrict__ inv_t,
             bf16* __restrict__ q_t) {
  __shared__ __align__(16) bf16 shW1[8 * 4096];   // W1 frags, 64KB
  __shared__ __align__(16) float shB[3][128];     // biases

  const int tid = threadIdx.x;
  const int l = tid & 63;
  const int w = tid >> 6;                 // wave 0..7
  const int g4 = l >> 4;
  const int r16 = l & 15;
  const int blk = blockIdx.x;
  const int n = blk >> 6;                 // task
  const int rg = blk & 63;                // row group of 256
  const int rowbase = rg * 256 + w * 32;

  const bf16* wbase = wstream + (size_t)n * 65536;
  // stage W1 (chunks 0..7) into LDS: 8 x 8KB
#pragma unroll
  for (int c = 0; c < 8; ++c)
    gload_lds16(wbase + c * 4096 + tid * 8, shW1 + c * 4096 + tid * 8);
  if (tid < 128) shB[0][tid] = b1[n * 128 + tid];
  else if (tid < 256) shB[1][tid - 128] = b2[n * 128 + (tid - 128)];
  else if (tid < 384) shB[2][tid - 256] = b3[n * 128 + (tid - 256)];

  int tidr[2];
  const float* srow[2];
#pragma unroll
  for (int rt = 0; rt < 2; ++rt) {
    int row = rowbase + rt * 16 + r16;
    tidr[rt] = task_id[row];
    srow[rt] = state + (size_t)row * 256;
  }
  __syncthreads();   // the only block-wide barrier

  const f32x4 fz = {0.f, 0.f, 0.f, 0.f};
  const int srcA = (g4 & 1) * 32 + r16;   // shfl source lane base
  const int hsel = g4 >> 1;               // which hc-half to take

  // ---- GEMM1: W1 (LDS) x state (global->reg, on-the-fly bf16), chunks 0..7
  f32x4 a1[2][8];
#pragma unroll
  for (int rt = 0; rt < 2; ++rt)
#pragma unroll
    for (int hc = 0; hc < 8; ++hc) a1[rt][hc] = fz;
#pragma unroll
  for (int ks = 0; ks < 8; ++ks) {
    bf16x8 sfr[2];
#pragma unroll
    for (int rt = 0; rt < 2; ++rt) {
      float4 x = *(const float4*)(srow[rt] + ks * 32 + g4 * 8);
      float4 y = *(const float4*)(srow[rt] + ks * 32 + g4 * 8 + 4);
      bf16x8 f;
      f[0] = (bf16)x.x; f[1] = (bf16)x.y; f[2] = (bf16)x.z; f[3] = (bf16)x.w;
      f[4] = (bf16)y.x; f[5] = (bf16)y.y; f[6] = (bf16)y.z; f[7] = (bf16)y.w;
      sfr[rt] = f;
    }
    __builtin_amdgcn_s_setprio(1);
#pragma unroll
    for (int hc = 0; hc < 8; ++hc) {
      bf16x8 wf = *(const bf16x8*)(shW1 + ks * 4096 + hc * 512 + l * 8);
      a1[0][hc] = mfma16(wf, sfr[0], a1[0][hc]);
      a1[1][hc] = mfma16(wf, sfr[1], a1[1][hc]);
    }
    __builtin_amdgcn_s_setprio(0);
  }
  // h1 = relu(T1 + b1), pack (lane-local)
  unsigned pk[2][8][2];
#pragma unroll
  for (int hc = 0; hc < 8; ++hc) {
    float4 bv = *(const float4*)&shB[0][hc * 16 + g4 * 4];
#pragma unroll
    for (int rt = 0; rt < 2; ++rt) {
      pk[rt][hc][0] = pack2(fmaxf(a1[rt][hc][0] + bv.x, 0.f),
                            fmaxf(a1[rt][hc][1] + bv.y, 0.f));
      pk[rt][hc][1] = pack2(fmaxf(a1[rt][hc][2] + bv.z, 0.f),
                            fmaxf(a1[rt][hc][3] + bv.w, 0.f));
    }
  }

  // ---- GEMM2: chunks 8..11, hb built upfront via shfl, W frags global->reg
  bf16x8 hb[2][4];
#pragma unroll
  for (int ks = 0; ks < 4; ++ks)
#pragma unroll
    for (int rt = 0; rt < 2; ++rt) {
      union { unsigned u[4]; bf16x8 v; } t;
#pragma unroll
      for (int m = 0; m < 4; ++m) {
        int src = srcA + (m >> 1) * 16;
        unsigned lo = __shfl(pk[rt][2 * ks][m & 1], src);
        unsigned hi = __shfl(pk[rt][2 * ks + 1][m & 1], src);
        t.u[m] = hsel ? hi : lo;
      }
      hb[rt][ks] = t.v;
    }
  const bf16* w2b = wbase + 8 * 4096;
  unsigned pk2[2][8][2];
#pragma unroll
  for (int hc = 0; hc < 8; ++hc) {
    f32x4 c0 = fz, c1 = fz;
    __builtin_amdgcn_s_setprio(1);
#pragma unroll
    for (int ks = 0; ks < 4; ++ks) {
      bf16x8 wf = *(const bf16x8*)(w2b + ks * 4096 + hc * 512 + l * 8);
      c0 = mfma16(wf, hb[0][ks], c0);
      c1 = mfma16(wf, hb[1][ks], c1);
    }
    __builtin_amdgcn_s_setprio(0);
    float4 bv = *(const float4*)&shB[1][hc * 16 + g4 * 4];
    pk2[0][hc][0] = pack2(fmaxf(c0[0] + bv.x, 0.f), fmaxf(c0[1] + bv.y, 0.f));
    pk2[0][hc][1] = pack2(fmaxf(c0[2] + bv.z, 0.f), fmaxf(c0[3] + bv.w, 0.f));
    pk2[1][hc][0] = pack2(fmaxf(c1[0] + bv.x, 0.f), fmaxf(c1[1] + bv.y, 0.f));
    pk2[1][hc][1] = pack2(fmaxf(c1[2] + bv.z, 0.f), fmaxf(c1[3] + bv.w, 0.f));
  }

  // ---- GEMM3: chunks 12..15; store q unnormalized per-hc, stream ssq/dot
  bf16x8 hb3[2][4];
#pragma unroll
  for (int ks = 0; ks < 4; ++ks)
#pragma unroll
    for (int rt = 0; rt < 2; ++rt) {
      union { unsigned u[4]; bf16x8 v; } t;
#pragma unroll
      for (int m = 0; m < 4; ++m) {
        int src = srcA + (m >> 1) * 16;
        unsigned lo = __shfl(pk2[rt][2 * ks][m & 1], src);
        unsigned hi = __shfl(pk2[rt][2 * ks + 1][m & 1], src);
        t.u[m] = hsel ? hi : lo;
      }
      hb3[rt][ks] = t.v;
    }
  const bf16* w3b = wbase + 12 * 4096;
  float ssq[2] = {0.f, 0.f}, dot[2] = {0.f, 0.f};
  bf16* qb0 = q_t + ((size_t)(rowbase + r16) * NTASK + n) * 128 + g4 * 4;
  bf16* qb1 = q_t + ((size_t)(rowbase + 16 + r16) * NTASK + n) * 128 + g4 * 4;
#pragma unroll
  for (int hc = 0; hc < 8; ++hc) {
    f32x4 c0 = fz, c1 = fz;
    __builtin_amdgcn_s_setprio(1);
#pragma unroll
    for (int ks = 0; ks < 4; ++ks) {
      bf16x8 wf = *(const bf16x8*)(w3b + ks * 4096 + hc * 512 + l * 8);
      c0 = mfma16(wf, hb3[0][ks], c0);
      c1 = mfma16(wf, hb3[1][ks], c1);
    }
    __builtin_amdgcn_s_setprio(0);
    float4 bv = *(const float4*)&shB[2][hc * 16 + g4 * 4];
    float4 lg0 = *(const float4*)&langn[(size_t)tidr[0] * 128 + hc * 16 + g4 * 4];
    float4 lg1 = *(const float4*)&langn[(size_t)tidr[1] * 128 + hc * 16 + g4 * 4];
    float q00 = c0[0] + bv.x, q01 = c0[1] + bv.y, q02 = c0[2] + bv.z, q03 = c0[3] + bv.w;
    float q10 = c1[0] + bv.x, q11 = c1[1] + bv.y, q12 = c1[2] + bv.z, q13 = c1[3] + bv.w;
    ssq[0] += q00 * q00 + q01 * q01 + q02 * q02 + q03 * q03;
    dot[0] += q00 * lg0.x + q01 * lg0.y + q02 * lg0.z + q03 * lg0.w;
    ssq[1] += q10 * q10 + q11 * q11 + q12 * q12 + q13 * q13;
    dot[1] += q10 * lg1.x + q11 * lg1.y + q12 * lg1.z + q13 * lg1.w;
    uint2 p0 = {pack2(q00, q01), pack2(q02, q03)};
    uint2 p1 = {pack2(q10, q11), pack2(q12, q13)};
    *(uint2*)(qb0 + hc * 16) = p0;
    *(uint2*)(qb1 + hc * 16) = p1;
  }
#pragma unroll
  for (int rt = 0; rt < 2; ++rt) {
    float s = ssq[rt], d = dot[rt];
    s += __shfl_xor(s, 16); s += __shfl_xor(s, 32);
    d += __shfl_xor(d, 16); d += __shfl_xor(d, 32);
    float inv = rsqrtf(s);
    if (g4 == 0) {
      int row = rowbase + rt * 16 + r16;
      cs_t[(size_t)row * NTASK + n] = d * inv;
      inv_t[(size_t)row * NTASK + n] = inv;
    }
  }
}

// ---------------- pass 3: per-row combine (1 wave per row) ----------------

__global__ void __launch_bounds__(256)
pass3_kernel(const float* __restrict__ state, const int* __restrict__ task_id,
             const float* __restrict__ prior, const float* __restrict__ cs_t,
             const float* __restrict__ inv_t, const bf16* __restrict__ q_t,
             float* __restrict__ out_rep, float* __restrict__ out_ltp,
             float* __restrict__ out_tgt, float* __restrict__ out_lat) {
  __shared__ float sppiv[4][NTASK];
  int w = threadIdx.x >> 6, l = threadIdx.x & 63;
  size_t row = (size_t)blockIdx.x * 4 + w;

  // softmax(prior) * inv  (inv folded so latent uses unnormalized q)
  float pv = (l < NTASK) ? prior[row * NTASK + l] : -INFINITY;
  float iv = (l < NTASK) ? inv_t[row * NTASK + l] : 0.0f;
  float m = pv;
#pragma unroll
  for (int mm = 1; mm < 64; mm <<= 1) m = fmaxf(m, __shfl_xor(m, mm));
  float e = (l < NTASK) ? expf(pv - m) : 0.0f;
  float s = e;
#pragma unroll
  for (int mm = 1; mm < 64; mm <<= 1) s += __shfl_xor(s, mm);
  if (l < NTASK) sppiv[w][l] = (e / s) * iv;

  // log_softmax(cos*10)
  float c = (l < NTASK) ? cs_t[row * NTASK + l] * 10.0f : -1e30f;
  float cm = c;
#pragma unroll
  for (int mm = 1; mm < 64; mm <<= 1) cm = fmaxf(cm, __shfl_xor(cm, mm));
  float ce = (l < NTASK) ? expf(c - cm) : 0.0f;
  float cs = ce;
#pragma unroll
  for (int mm = 1; mm < 64; mm <<= 1) cs += __shfl_xor(cs, mm);
  if (l < NTASK) out_ltp[row * NTASK + l] = c - cm - logf(cs);

  int tg = task_id[row];
  float ivt = __shfl(iv, tg);
  __syncthreads();

  // latent: lane covers cols {2l, 2l+1}; q_t row-major [row][34][128]
  const bf16* qrow = q_t + row * NTASK * 128;
  float lat0 = 0.f, lat1 = 0.f;
#pragma unroll
  for (int n = 0; n < NTASK; ++n) {
    float pw = sppiv[w][n];
    union { unsigned u; __bf16 h[2]; } q;
    q.u = *(const unsigned*)(qrow + n * 128 + 2 * l);
    lat0 += pw * (float)q.h[0];
    lat1 += pw * (float)q.h[1];
  }
  float2 lv = {lat0, lat1};
  *(float2*)(out_lat + row * 128 + 2 * l) = lv;
  *(float2*)(out_rep + row * 384 + 256 + 2 * l) = lv;

  // latent_target = q[tg] * inv[tg]
  union { unsigned u; __bf16 h[2]; } qt;
  qt.u = *(const unsigned*)(qrow + tg * 128 + 2 * l);
  float2 tv = {(float)qt.h[0] * ivt, (float)qt.h[1] * ivt};
  *(float2*)(out_tgt + row * 128 + 2 * l) = tv;

  // state passthrough
  float4 sv = *(const float4*)(state + row * 256 + l * 4);
  *(float4*)(out_rep + row * 384 + l * 4) = sv;
}

// ---------------- launch ----------------

extern "C" void kernel_launch(void* const* d_in, const int* in_sizes, int n_in,
                              void* d_out, int out_size, void* d_ws, size_t ws_size,
                              hipStream_t stream) {
  (void)in_sizes; (void)n_in; (void)out_size; (void)ws_size;
  const float* state = (const float*)d_in[0];
  const int* task_id = (const int*)d_in[1];
  const float* prior = (const float*)d_in[2];
  const float* W1 = (const float*)d_in[3];
  const float* b1 = (const float*)d_in[4];
  const float* W2 = (const float*)d_in[5];
  const float* b2 = (const float*)d_in[6];
  const float* W3 = (const float*)d_in[7];
  const float* b3 = (const float*)d_in[8];
  const float* lang = (const float*)d_in[9];

  char* ws = (char*)d_ws;
  bf16* wstream = (bf16*)(ws + 0);          //   4,456,448 B
  float* langn  = (float*)(ws + 4456448);   //      17,408 B
  float* cs_t   = (float*)(ws + 4473856);   //   2,228,224 B  [16384][34] f32
  float* inv_t  = (float*)(ws + 6702080);   //   2,228,224 B  [16384][34] f32
  bf16* q_t     = (bf16*)(ws + 8930304);    // 142,606,336 B  [16384][34][128] bf16
                                            // total 151,536,640 B

  float* out = (float*)d_out;
  float* out_rep = out;                 // [B,384]
  float* out_ltp = out + 6291456;       // [B,34]
  float* out_tgt = out + 6848512;       // [B,128]
  float* out_lat = out + 8945664;       // [B,128]

  prep_w_all<<<1088, 256, 0, stream>>>(W1, W2, W3, wstream);
  prep_langn<<<NTASK, 128, 0, stream>>>(lang, langn);
  pass1_kernel<<<NTASK * 64, 512, 0, stream>>>(task_id, b1, b2, b3, wstream,
                                               state, langn, cs_t, inv_t, q_t);
  pass3_kernel<<<4096, 256, 0, stream>>>(state, task_id, prior, cs_t, inv_t, q_t,
                                         out_rep, out_ltp, out_tgt, out_lat);
}

// Round 7
// 193.230 us; speedup vs baseline: 1.1336x; 1.1336x over previous
//
#include <hip/hip_runtime.h>
#include <hip/hip_bf16.h>
#include <cstdint>
#include <cstddef>

typedef __bf16 bf16;
typedef __attribute__((ext_vector_type(8))) __bf16 bf16x8;
typedef __attribute__((ext_vector_type(16))) float f32x16;

static_assert(sizeof(bf16x8) == 16, "bf16x8 must be 16B");

#define NTASK 34
#define BTOT 16384
#define WSTRIDE 73728   // bf16 elems per task stream: 140KB real + 4KB pad = 144KB

__device__ __forceinline__ f32x16 mfma32(bf16x8 a, bf16x8 b, f32x16 c) {
  return __builtin_amdgcn_mfma_f32_32x32x16_bf16(a, b, c, 0, 0, 0);
}

__device__ __forceinline__ void gload_lds16(const void* g, void* l) {
  __builtin_amdgcn_global_load_lds((__attribute__((address_space(1))) void*)g,
                                   (__attribute__((address_space(3))) void*)l,
                                   16, 0, 0);
}

__device__ __forceinline__ unsigned pack2(float lo, float hi) {
  union { __bf16 h[2]; unsigned u; } v;
  v.h[0] = (__bf16)lo; v.h[1] = (__bf16)hi;
  return v.u;
}

// vdst hi-lanes <-> vsrc lo-lanes exchange (both modified)
__device__ __forceinline__ void pl32swap(unsigned &a, unsigned &b) {
  asm volatile("v_permlane32_swap_b32 %0, %1" : "+v"(a), "+v"(b));
}

// ---------------- prep kernels ----------------

// Weights -> 32x32 MFMA A-frag blocks (1KB each), per-task stream.
// Block layout per task: W1: blocks mt*17+ks (ks 0..16, ks=16 = bias row);
// W2: 68 + mt*9 + ks; W3: 104 + mt*9 + ks. Frag elem (l,j):
//   ks<real: W[k = ks*16 + (l>>5)*8 + j][col = mt*32 + (l&31)]
//   ks==real: j==0 && l<32 ? bias[col] : 0       (K-augment bias row)
__global__ void prep_w_all(const float* __restrict__ W1, const float* __restrict__ W2,
                           const float* __restrict__ W3, const float* __restrict__ b1,
                           const float* __restrict__ b2, const float* __restrict__ b3,
                           bf16* __restrict__ dst) {
  int idx = blockIdx.x * 256 + threadIdx.x;    // 34*140*64 = 304640 exact
  int n = idx / (140 * 64);
  int r = idx - n * (140 * 64);
  int bb = r >> 6, l = r & 63;
  const float *W, *bias; int real, mt, ks, Kt;
  if (bb < 68)       { W = W1; bias = b1; mt = bb / 17; ks = bb - mt * 17; real = 16; Kt = 256; }
  else if (bb < 104) { W = W2; bias = b2; int t = bb - 68;  mt = t / 9; ks = t - mt * 9; real = 8; Kt = 128; }
  else               { W = W3; bias = b3; int t = bb - 104; mt = t / 9; ks = t - mt * 9; real = 8; Kt = 128; }
  int col = mt * 32 + (l & 31);
  bf16x8 v;
  if (ks < real) {
    int k0 = ks * 16 + ((l >> 5) << 3);
    const float* s = W + ((size_t)n * Kt + k0) * 128 + col;
#pragma unroll
    for (int j = 0; j < 8; ++j) v[j] = (bf16)s[(size_t)j * 128];
  } else {
#pragma unroll
    for (int j = 0; j < 8; ++j) v[j] = (bf16)0.f;
    if (l < 32) v[0] = (bf16)bias[n * 128 + col];
  }
  *(bf16x8*)(dst + (size_t)n * WSTRIDE + bb * 512 + l * 8) = v;
}

// state -> 32x32 B-frag blocks: (rb, ks) 1KB block, elem (l,j) =
// state[rb*32 + (l&31)][ks*16 + (l>>5)*8 + j]
__global__ void prep_state_frags(const float* __restrict__ state, bf16* __restrict__ dst) {
  int idx = blockIdx.x * 256 + threadIdx.x;   // 524288 exact
  int rb = idx >> 10;
  int r = idx & 1023;
  int ks = r >> 6;
  int l = r & 63;
  int b = rb * 32 + (l & 31);
  int k0 = ks * 16 + ((l >> 5) << 3);
  const float* s = state + (size_t)b * 256 + k0;
  bf16x8 v;
#pragma unroll
  for (int j = 0; j < 8; ++j) v[j] = (bf16)s[j];
  *(bf16x8*)(dst + (size_t)(rb * 16 + ks) * 512 + l * 8) = v;
}

__global__ void prep_langn(const float* __restrict__ lang, float* __restrict__ out) {
  __shared__ float red[2];
  int n = blockIdx.x;
  int t = threadIdx.x;                        // 128 threads
  float v = lang[(size_t)n * 128 + t];
  float ss = v * v;
#pragma unroll
  for (int m = 1; m < 64; m <<= 1) ss += __shfl_xor(ss, m);
  if ((t & 63) == 0) red[t >> 6] = ss;
  __syncthreads();
  float s = red[0] + red[1];
  float sc = 1.0f / fmaxf(sqrtf(s), 1e-8f);
  out[(size_t)n * 128 + t] = v * sc;
}

// ---------------- pass 1 ----------------
// Task-per-block, 1024 thr = 16 waves, 32 rows/wave, barrier-free compute.
// 32x32x16 swapped MFMA: T[hcol][b] = W^T x^T; C: col=b=l&31,
// hcol = mt*32 + (r&3) + 8*(r>>2) + 4*(l>>5). K-augmented bias.
// Transitions: cvt_pk + v_permlane32_swap (register-only, no LDS).

__global__ void __launch_bounds__(1024)
pass1_kernel(const int* __restrict__ task_id, const bf16* __restrict__ wstream,
             const bf16* __restrict__ sf, const float* __restrict__ langn,
             float* __restrict__ cs_t, float* __restrict__ inv_t,
             bf16* __restrict__ q_t) {
  __shared__ __align__(16) bf16 shW[WSTRIDE];   // 144KB weight stream

  const int tid = threadIdx.x;
  const int l = tid & 63;
  const int w = tid >> 6;          // wave 0..15
  const int hi = l >> 5;
  const int b = l & 31;
  const int n = blockIdx.x >> 5;   // task
  const int rg = blockIdx.x & 31;  // 512-row group
  const int row = rg * 512 + w * 32 + b;
  const int rb = rg * 16 + w;      // 32-row block index

  int tidn = task_id[row];

  // stage full 144KB stream: 9 x 16KB issues (W1+bias = first 69.6KB)
  const bf16* wbase = wstream + (size_t)n * WSTRIDE;
#pragma unroll
  for (int c = 0; c < 9; ++c)
    gload_lds16(wbase + c * 8192 + tid * 8, shW + c * 8192 + tid * 8);

  // const "1" B-frag for the bias K-augment step
  union { unsigned u[4]; bf16x8 v; } cf;
  cf.u[0] = (l < 32) ? 0x3f80u : 0u;
  cf.u[1] = 0u; cf.u[2] = 0u; cf.u[3] = 0u;

  // barrier 1: W1 landed (own c0..c4 done per-wave => union covers W1)
  asm volatile("s_waitcnt vmcnt(4)" ::: "memory");
  __builtin_amdgcn_s_barrier();

  f32x16 z;
#pragma unroll
  for (int i = 0; i < 16; ++i) z[i] = 0.f;
  f32x16 acc[4] = {z, z, z, z};

  // ---- GEMM1: 16 data ksteps + const kstep, state frags rolling 8-deep
  const bf16* sbase = sf + (size_t)rb * 16 * 512 + l * 8;
  bf16x8 sb[8];
#pragma unroll
  for (int i = 0; i < 8; ++i) sb[i] = *(const bf16x8*)(sbase + i * 512);
#pragma unroll
  for (int ks = 0; ks < 16; ++ks) {
    bf16x8 sv = sb[ks & 7];
    if (ks < 8) sb[ks & 7] = *(const bf16x8*)(sbase + (ks + 8) * 512);
    __builtin_amdgcn_s_setprio(1);
#pragma unroll
    for (int mt = 0; mt < 4; ++mt) {
      bf16x8 wf = *(const bf16x8*)(shW + ((mt * 17 + ks) << 9) + l * 8);
      acc[mt] = mfma32(wf, sv, acc[mt]);
    }
    __builtin_amdgcn_s_setprio(0);
  }
#pragma unroll
  for (int mt = 0; mt < 4; ++mt) {
    bf16x8 wf = *(const bf16x8*)(shW + ((mt * 17 + 16) << 9) + l * 8);
    acc[mt] = mfma32(wf, cf.v, acc[mt]);
  }

  // ---- transition 1: relu + pack + permlane swaps -> 8 B-frags (reg only)
  bf16x8 f2[8];
#pragma unroll
  for (int mt = 0; mt < 4; ++mt) {
    unsigned p[8];
#pragma unroll
    for (int q = 0; q < 4; ++q) {
      p[2 * q]     = pack2(fmaxf(acc[mt][4 * q + 0], 0.f), fmaxf(acc[mt][4 * q + 1], 0.f));
      p[2 * q + 1] = pack2(fmaxf(acc[mt][4 * q + 2], 0.f), fmaxf(acc[mt][4 * q + 3], 0.f));
    }
    pl32swap(p[0], p[2]); pl32swap(p[1], p[3]);
    pl32swap(p[4], p[6]); pl32swap(p[5], p[7]);
    union { unsigned u[4]; bf16x8 v; } e, o;
    e.u[0] = p[0]; e.u[1] = p[1]; e.u[2] = p[2]; e.u[3] = p[3];
    o.u[0] = p[4]; o.u[1] = p[5]; o.u[2] = p[6]; o.u[3] = p[7];
    f2[2 * mt] = e.v; f2[2 * mt + 1] = o.v;
  }

  // barrier 2: rest of stream (W2/W3) landed
  asm volatile("s_waitcnt vmcnt(0)" ::: "memory");
  __builtin_amdgcn_s_barrier();

  // ---- GEMM2: 8 data ksteps + const
#pragma unroll
  for (int mt = 0; mt < 4; ++mt) acc[mt] = z;
#pragma unroll
  for (int ks = 0; ks < 8; ++ks) {
    __builtin_amdgcn_s_setprio(1);
#pragma unroll
    for (int mt = 0; mt < 4; ++mt) {
      bf16x8 wf = *(const bf16x8*)(shW + ((68 + mt * 9 + ks) << 9) + l * 8);
      acc[mt] = mfma32(wf, f2[ks], acc[mt]);
    }
    __builtin_amdgcn_s_setprio(0);
  }
#pragma unroll
  for (int mt = 0; mt < 4; ++mt) {
    bf16x8 wf = *(const bf16x8*)(shW + ((68 + mt * 9 + 8) << 9) + l * 8);
    acc[mt] = mfma32(wf, cf.v, acc[mt]);
  }

  // ---- transition 2
  bf16x8 f3[8];
#pragma unroll
  for (int mt = 0; mt < 4; ++mt) {
    unsigned p[8];
#pragma unroll
    for (int q = 0; q < 4; ++q) {
      p[2 * q]     = pack2(fmaxf(acc[mt][4 * q + 0], 0.f), fmaxf(acc[mt][4 * q + 1], 0.f));
      p[2 * q + 1] = pack2(fmaxf(acc[mt][4 * q + 2], 0.f), fmaxf(acc[mt][4 * q + 3], 0.f));
    }
    pl32swap(p[0], p[2]); pl32swap(p[1], p[3]);
    pl32swap(p[4], p[6]); pl32swap(p[5], p[7]);
    union { unsigned u[4]; bf16x8 v; } e, o;
    e.u[0] = p[0]; e.u[1] = p[1]; e.u[2] = p[2]; e.u[3] = p[3];
    o.u[0] = p[4]; o.u[1] = p[5]; o.u[2] = p[6]; o.u[3] = p[7];
    f3[2 * mt] = e.v; f3[2 * mt + 1] = o.v;
  }

  // ---- GEMM3: 8 data ksteps + const (no activation; bias folded)
#pragma unroll
  for (int mt = 0; mt < 4; ++mt) acc[mt] = z;
#pragma unroll
  for (int ks = 0; ks < 8; ++ks) {
    __builtin_amdgcn_s_setprio(1);
#pragma unroll
    for (int mt = 0; mt < 4; ++mt) {
      bf16x8 wf = *(const bf16x8*)(shW + ((104 + mt * 9 + ks) << 9) + l * 8);
      acc[mt] = mfma32(wf, f3[ks], acc[mt]);
    }
    __builtin_amdgcn_s_setprio(0);
  }
#pragma unroll
  for (int mt = 0; mt < 4; ++mt) {
    bf16x8 wf = *(const bf16x8*)(shW + ((104 + mt * 9 + 8) << 9) + l * 8);
    acc[mt] = mfma32(wf, cf.v, acc[mt]);
  }

  // ---- epilogue: lane l holds q[64 hcols][b]; partner (l^32) has the rest
  float ssq = 0.f, dot = 0.f;
  const float* lgb = langn + (size_t)tidn * 128;
#pragma unroll
  for (int mt = 0; mt < 4; ++mt)
#pragma unroll
    for (int q = 0; q < 4; ++q) {
      float4 lg = *(const float4*)(lgb + mt * 32 + q * 8 + 4 * hi);
      float a0 = acc[mt][4 * q + 0], a1 = acc[mt][4 * q + 1];
      float a2 = acc[mt][4 * q + 2], a3 = acc[mt][4 * q + 3];
      ssq += a0 * a0 + a1 * a1 + a2 * a2 + a3 * a3;
      dot += a0 * lg.x + a1 * lg.y + a2 * lg.z + a3 * lg.w;
    }
  ssq += __shfl_xor(ssq, 32);
  dot += __shfl_xor(dot, 32);
  float inv = rsqrtf(ssq);
  if (l < 32) {
    cs_t[(size_t)row * NTASK + n] = dot * inv;
    inv_t[(size_t)row * NTASK + n] = inv;
  }
  bf16* qrow = q_t + ((size_t)row * NTASK + n) * 128;
#pragma unroll
  for (int mt = 0; mt < 4; ++mt)
#pragma unroll
    for (int q = 0; q < 4; ++q) {
      uint2 qp;
      qp.x = pack2(acc[mt][4 * q + 0], acc[mt][4 * q + 1]);
      qp.y = pack2(acc[mt][4 * q + 2], acc[mt][4 * q + 3]);
      *(uint2*)(qrow + mt * 32 + q * 8 + 4 * hi) = qp;
    }
}

// ---------------- pass 3: per-row combine (1 wave per row) ----------------

__global__ void __launch_bounds__(256)
pass3_kernel(const float* __restrict__ state, const int* __restrict__ task_id,
             const float* __restrict__ prior, const float* __restrict__ cs_t,
             const float* __restrict__ inv_t, const bf16* __restrict__ q_t,
             float* __restrict__ out_rep, float* __restrict__ out_ltp,
             float* __restrict__ out_tgt, float* __restrict__ out_lat) {
  __shared__ float sppiv[4][NTASK];
  int w = threadIdx.x >> 6, l = threadIdx.x & 63;
  size_t row = (size_t)blockIdx.x * 4 + w;

  // softmax(prior) * inv (inv folded so latent uses unnormalized q)
  float pv = (l < NTASK) ? prior[row * NTASK + l] : -INFINITY;
  float iv = (l < NTASK) ? inv_t[row * NTASK + l] : 0.0f;
  float m = pv;
#pragma unroll
  for (int mm = 1; mm < 64; mm <<= 1) m = fmaxf(m, __shfl_xor(m, mm));
  float e = (l < NTASK) ? expf(pv - m) : 0.0f;
  float s = e;
#pragma unroll
  for (int mm = 1; mm < 64; mm <<= 1) s += __shfl_xor(s, mm);
  if (l < NTASK) sppiv[w][l] = (e / s) * iv;

  // log_softmax(cos*10)
  float c = (l < NTASK) ? cs_t[row * NTASK + l] * 10.0f : -1e30f;
  float cm = c;
#pragma unroll
  for (int mm = 1; mm < 64; mm <<= 1) cm = fmaxf(cm, __shfl_xor(cm, mm));
  float ce = (l < NTASK) ? expf(c - cm) : 0.0f;
  float cs = ce;
#pragma unroll
  for (int mm = 1; mm < 64; mm <<= 1) cs += __shfl_xor(cs, mm);
  if (l < NTASK) out_ltp[row * NTASK + l] = c - cm - logf(cs);

  int tg = task_id[row];
  float ivt = __shfl(iv, tg);
  __syncthreads();

  // latent: lane covers cols {2l, 2l+1}; q_t row-major [row][34][128]
  const bf16* qrow = q_t + row * NTASK * 128;
  float lat0 = 0.f, lat1 = 0.f;
#pragma unroll
  for (int n = 0; n < NTASK; ++n) {
    float pw = sppiv[w][n];
    union { unsigned u; __bf16 h[2]; } q;
    q.u = *(const unsigned*)(qrow + n * 128 + 2 * l);
    lat0 += pw * (float)q.h[0];
    lat1 += pw * (float)q.h[1];
  }
  float2 lv = {lat0, lat1};
  *(float2*)(out_lat + row * 128 + 2 * l) = lv;
  *(float2*)(out_rep + row * 384 + 256 + 2 * l) = lv;

  // latent_target = q[tg] * inv[tg]
  union { unsigned u; __bf16 h[2]; } qt;
  qt.u = *(const unsigned*)(qrow + tg * 128 + 2 * l);
  float2 tv = {(float)qt.h[0] * ivt, (float)qt.h[1] * ivt};
  *(float2*)(out_tgt + row * 128 + 2 * l) = tv;

  // state passthrough
  float4 sv = *(const float4*)(state + row * 256 + l * 4);
  *(float4*)(out_rep + row * 384 + l * 4) = sv;
}

// ---------------- launch ----------------

extern "C" void kernel_launch(void* const* d_in, const int* in_sizes, int n_in,
                              void* d_out, int out_size, void* d_ws, size_t ws_size,
                              hipStream_t stream) {
  (void)in_sizes; (void)n_in; (void)out_size; (void)ws_size;
  const float* state = (const float*)d_in[0];
  const int* task_id = (const int*)d_in[1];
  const float* prior = (const float*)d_in[2];
  const float* W1 = (const float*)d_in[3];
  const float* b1 = (const float*)d_in[4];
  const float* W2 = (const float*)d_in[5];
  const float* b2 = (const float*)d_in[6];
  const float* W3 = (const float*)d_in[7];
  const float* b3 = (const float*)d_in[8];
  const float* lang = (const float*)d_in[9];

  char* ws = (char*)d_ws;
  bf16* wstream = (bf16*)(ws + 0);           //   5,013,504 B (34 x 144KB)
  bf16* sf      = (bf16*)(ws + 5013504);     //   8,388,608 B
  float* langn  = (float*)(ws + 13402112);   //      17,408 B
  float* cs_t   = (float*)(ws + 13419520);   //   2,228,224 B [16384][34]
  float* inv_t  = (float*)(ws + 15647744);   //   2,228,224 B [16384][34]
  bf16* q_t     = (bf16*)(ws + 17875968);    // 142,606,336 B [16384][34][128]
                                             // total 160,482,304 B

  float* out = (float*)d_out;
  float* out_rep = out;                 // [B,384]
  float* out_ltp = out + 6291456;       // [B,34]
  float* out_tgt = out + 6848512;       // [B,128]
  float* out_lat = out + 8945664;       // [B,128]

  prep_w_all<<<1190, 256, 0, stream>>>(W1, W2, W3, b1, b2, b3, wstream);
  prep_state_frags<<<2048, 256, 0, stream>>>(state, sf);
  prep_langn<<<NTASK, 128, 0, stream>>>(lang, langn);
  pass1_kernel<<<NTASK * 32, 1024, 0, stream>>>(task_id, wstream, sf, langn,
                                                cs_t, inv_t, q_t);
  pass3_kernel<<<4096, 256, 0, stream>>>(state, task_id, prior, cs_t, inv_t, q_t,
                                         out_rep, out_ltp, out_tgt, out_lat);
}

// Round 8
// 179.566 us; speedup vs baseline: 1.2198x; 1.0761x over previous
//
#include <hip/hip_runtime.h>
#include <hip/hip_bf16.h>
#include <cstdint>
#include <cstddef>

typedef __bf16 bf16;
typedef __attribute__((ext_vector_type(8))) __bf16 bf16x8;
typedef __attribute__((ext_vector_type(16))) float f32x16;

static_assert(sizeof(bf16x8) == 16, "bf16x8 must be 16B");

#define NTASK 34
#define BTOT 16384
#define WSTRIDE 73728   // bf16 elems per task stream: 140KB real + 4KB pad = 144KB

__device__ __forceinline__ f32x16 mfma32(bf16x8 a, bf16x8 b, f32x16 c) {
  return __builtin_amdgcn_mfma_f32_32x32x16_bf16(a, b, c, 0, 0, 0);
}

__device__ __forceinline__ void gload_lds16(const void* g, void* l) {
  __builtin_amdgcn_global_load_lds((__attribute__((address_space(1))) void*)g,
                                   (__attribute__((address_space(3))) void*)l,
                                   16, 0, 0);
}

__device__ __forceinline__ unsigned pack2(float lo, float hi) {
  union { __bf16 h[2]; unsigned u; } v;
  v.h[0] = (__bf16)lo; v.h[1] = (__bf16)hi;
  return v.u;
}

// vdst hi-lanes <-> vsrc lo-lanes exchange (both modified)
__device__ __forceinline__ void pl32swap(unsigned &a, unsigned &b) {
  asm volatile("v_permlane32_swap_b32 %0, %1" : "+v"(a), "+v"(b));
}

// ---------------- prep kernels ----------------

// Weights -> 32x32 MFMA A-frag blocks (1KB each), per-task stream.
// W1: blocks mt*17+ks (ks 0..16, ks=16 = bias row); W2: 68+mt*9+ks; W3: 104+mt*9+ks.
__global__ void prep_w_all(const float* __restrict__ W1, const float* __restrict__ W2,
                           const float* __restrict__ W3, const float* __restrict__ b1,
                           const float* __restrict__ b2, const float* __restrict__ b3,
                           bf16* __restrict__ dst) {
  int idx = blockIdx.x * 256 + threadIdx.x;    // 34*140*64 = 304640 exact
  int n = idx / (140 * 64);
  int r = idx - n * (140 * 64);
  int bb = r >> 6, l = r & 63;
  const float *W, *bias; int real, mt, ks, Kt;
  if (bb < 68)       { W = W1; bias = b1; mt = bb / 17; ks = bb - mt * 17; real = 16; Kt = 256; }
  else if (bb < 104) { W = W2; bias = b2; int t = bb - 68;  mt = t / 9; ks = t - mt * 9; real = 8; Kt = 128; }
  else               { W = W3; bias = b3; int t = bb - 104; mt = t / 9; ks = t - mt * 9; real = 8; Kt = 128; }
  int col = mt * 32 + (l & 31);
  bf16x8 v;
  if (ks < real) {
    int k0 = ks * 16 + ((l >> 5) << 3);
    const float* s = W + ((size_t)n * Kt + k0) * 128 + col;
#pragma unroll
    for (int j = 0; j < 8; ++j) v[j] = (bf16)s[(size_t)j * 128];
  } else {
#pragma unroll
    for (int j = 0; j < 8; ++j) v[j] = (bf16)0.f;
    if (l < 32) v[0] = (bf16)bias[n * 128 + col];
  }
  *(bf16x8*)(dst + (size_t)n * WSTRIDE + bb * 512 + l * 8) = v;
}

// state -> 32x32 B-frag blocks: (rb, ks) 1KB block, elem (l,j) =
// state[rb*32 + (l&31)][ks*16 + (l>>5)*8 + j]
__global__ void prep_state_frags(const float* __restrict__ state, bf16* __restrict__ dst) {
  int idx = blockIdx.x * 256 + threadIdx.x;   // 524288 exact
  int rb = idx >> 10;
  int r = idx & 1023;
  int ks = r >> 6;
  int l = r & 63;
  int b = rb * 32 + (l & 31);
  int k0 = ks * 16 + ((l >> 5) << 3);
  const float* s = state + (size_t)b * 256 + k0;
  bf16x8 v;
#pragma unroll
  for (int j = 0; j < 8; ++j) v[j] = (bf16)s[j];
  *(bf16x8*)(dst + (size_t)(rb * 16 + ks) * 512 + l * 8) = v;
}

__global__ void prep_langn(const float* __restrict__ lang, float* __restrict__ out) {
  __shared__ float red[2];
  int n = blockIdx.x;
  int t = threadIdx.x;                        // 128 threads
  float v = lang[(size_t)n * 128 + t];
  float ss = v * v;
#pragma unroll
  for (int m = 1; m < 64; m <<= 1) ss += __shfl_xor(ss, m);
  if ((t & 63) == 0) red[t >> 6] = ss;
  __syncthreads();
  float s = red[0] + red[1];
  float sc = 1.0f / fmaxf(sqrtf(s), 1e-8f);
  out[(size_t)n * 128 + t] = v * sc;
}

// ---------------- pass 1 ----------------
// Task-per-block, 512 thr = 8 waves, 64 rows/wave (2 x 32-row tiles).
// 256-reg budget (launch_bounds 512,2): acc 128 AGPR + pipelined wf reads.
// Swapped 32x32x16 MFMA, K-augmented bias, permlane register transitions.
// Epilogue: shW reused as staging for coalesced q_t stores.

__global__ void __launch_bounds__(512, 2)
pass1_kernel(const int* __restrict__ task_id, const bf16* __restrict__ wstream,
             const bf16* __restrict__ sf, const float* __restrict__ langn,
             float* __restrict__ cs_t, float* __restrict__ inv_t,
             bf16* __restrict__ q_t) {
  __shared__ __align__(16) bf16 shW[WSTRIDE];   // 144KB weights / q staging

  const int tid = threadIdx.x;
  const int l = tid & 63;
  const int w = tid >> 6;          // wave 0..7
  const int hi = l >> 5;
  const int b = l & 31;
  const int n = blockIdx.x >> 5;   // task
  const int rg = blockIdx.x & 31;  // 512-row group
  const int lr0 = w * 64 + b;      // local row, tile0 (tile1 = +32)
  const int row0 = rg * 512 + lr0;
  const int rb0 = rg * 16 + w * 2; // frag-block index tile0

  int tidn0 = task_id[row0];
  int tidn1 = task_id[row0 + 32];

  // B-frag rolling buffers (issued BEFORE stages so vmcnt(9) covers them too)
  const bf16* sb0 = sf + (size_t)rb0 * 8192 + l * 8;
  const bf16* sb1 = sb0 + 8192;
  bf16x8 s0[4], s1[4];
#pragma unroll
  for (int i = 0; i < 4; ++i) {
    s0[i] = *(const bf16x8*)(sb0 + i * 512);
    s1[i] = *(const bf16x8*)(sb1 + i * 512);
  }

  // stage full 144KB stream: 18 x 8KB (W1+bias = first 69.6KB, inside c0..c8)
  const bf16* wbase = wstream + (size_t)n * WSTRIDE;
#pragma unroll
  for (int c = 0; c < 18; ++c)
    gload_lds16(wbase + c * 4096 + tid * 8, shW + c * 4096 + tid * 8);

  // const "1" B-frag for the bias K-augment step
  union { unsigned u[4]; bf16x8 v; } cf;
  cf.u[0] = (l < 32) ? 0x3f80u : 0u;
  cf.u[1] = 0u; cf.u[2] = 0u; cf.u[3] = 0u;

  // barrier 1: W1+bias landed (9 newest stages may remain in flight)
  asm volatile("s_waitcnt vmcnt(9)" ::: "memory");
  __builtin_amdgcn_s_barrier();

  f32x16 z;
#pragma unroll
  for (int i = 0; i < 16; ++i) z[i] = 0.f;
  f32x16 acc0[4] = {z, z, z, z};
  f32x16 acc1[4] = {z, z, z, z};

  // ---- GEMM1: 16 data ksteps + const kstep
#pragma unroll
  for (int ks = 0; ks < 16; ++ks) {
    bf16x8 sv0 = s0[ks & 3], sv1 = s1[ks & 3];
    if (ks < 12) {
      s0[ks & 3] = *(const bf16x8*)(sb0 + (ks + 4) * 512);
      s1[ks & 3] = *(const bf16x8*)(sb1 + (ks + 4) * 512);
    }
    __builtin_amdgcn_s_setprio(1);
#pragma unroll
    for (int mt = 0; mt < 4; ++mt) {
      bf16x8 wf = *(const bf16x8*)(shW + ((mt * 17 + ks) << 9) + l * 8);
      acc0[mt] = mfma32(wf, sv0, acc0[mt]);
      acc1[mt] = mfma32(wf, sv1, acc1[mt]);
    }
    __builtin_amdgcn_s_setprio(0);
  }
#pragma unroll
  for (int mt = 0; mt < 4; ++mt) {
    bf16x8 wf = *(const bf16x8*)(shW + ((mt * 17 + 16) << 9) + l * 8);
    acc0[mt] = mfma32(wf, cf.v, acc0[mt]);
    acc1[mt] = mfma32(wf, cf.v, acc1[mt]);
  }

  // ---- transition: relu + pack + permlane swaps -> 8 B-frags per tile
  auto transition = [&](f32x16* acc, bf16x8* f) {
#pragma unroll
    for (int mt = 0; mt < 4; ++mt) {
      unsigned p[8];
#pragma unroll
      for (int q = 0; q < 4; ++q) {
        p[2 * q]     = pack2(fmaxf(acc[mt][4 * q + 0], 0.f), fmaxf(acc[mt][4 * q + 1], 0.f));
        p[2 * q + 1] = pack2(fmaxf(acc[mt][4 * q + 2], 0.f), fmaxf(acc[mt][4 * q + 3], 0.f));
      }
      pl32swap(p[0], p[2]); pl32swap(p[1], p[3]);
      pl32swap(p[4], p[6]); pl32swap(p[5], p[7]);
      union { unsigned u[4]; bf16x8 v; } e, o;
      e.u[0] = p[0]; e.u[1] = p[1]; e.u[2] = p[2]; e.u[3] = p[3];
      o.u[0] = p[4]; o.u[1] = p[5]; o.u[2] = p[6]; o.u[3] = p[7];
      f[2 * mt] = e.v; f[2 * mt + 1] = o.v;
    }
  };

  bf16x8 f2a[8], f2b[8];
  transition(acc0, f2a);
  transition(acc1, f2b);

  // barrier 2: full stream landed
  asm volatile("s_waitcnt vmcnt(0)" ::: "memory");
  __builtin_amdgcn_s_barrier();

  // ---- GEMM2: 8 data ksteps + const
#pragma unroll
  for (int mt = 0; mt < 4; ++mt) { acc0[mt] = z; acc1[mt] = z; }
#pragma unroll
  for (int ks = 0; ks < 8; ++ks) {
    __builtin_amdgcn_s_setprio(1);
#pragma unroll
    for (int mt = 0; mt < 4; ++mt) {
      bf16x8 wf = *(const bf16x8*)(shW + ((68 + mt * 9 + ks) << 9) + l * 8);
      acc0[mt] = mfma32(wf, f2a[ks], acc0[mt]);
      acc1[mt] = mfma32(wf, f2b[ks], acc1[mt]);
    }
    __builtin_amdgcn_s_setprio(0);
  }
#pragma unroll
  for (int mt = 0; mt < 4; ++mt) {
    bf16x8 wf = *(const bf16x8*)(shW + ((68 + mt * 9 + 8) << 9) + l * 8);
    acc0[mt] = mfma32(wf, cf.v, acc0[mt]);
    acc1[mt] = mfma32(wf, cf.v, acc1[mt]);
  }

  bf16x8 f3a[8], f3b[8];
  transition(acc0, f3a);
  transition(acc1, f3b);

  // ---- GEMM3: 8 data ksteps + const (bias folded, no activation)
#pragma unroll
  for (int mt = 0; mt < 4; ++mt) { acc0[mt] = z; acc1[mt] = z; }
#pragma unroll
  for (int ks = 0; ks < 8; ++ks) {
    __builtin_amdgcn_s_setprio(1);
#pragma unroll
    for (int mt = 0; mt < 4; ++mt) {
      bf16x8 wf = *(const bf16x8*)(shW + ((104 + mt * 9 + ks) << 9) + l * 8);
      acc0[mt] = mfma32(wf, f3a[ks], acc0[mt]);
      acc1[mt] = mfma32(wf, f3b[ks], acc1[mt]);
    }
    __builtin_amdgcn_s_setprio(0);
  }
#pragma unroll
  for (int mt = 0; mt < 4; ++mt) {
    bf16x8 wf = *(const bf16x8*)(shW + ((104 + mt * 9 + 8) << 9) + l * 8);
    acc0[mt] = mfma32(wf, cf.v, acc0[mt]);
    acc1[mt] = mfma32(wf, cf.v, acc1[mt]);
  }

  // ---- epilogue: ssq/dot per tile (lane holds 64 of 128 cols; partner l^32 rest)
  {
    float ssq0 = 0.f, dot0 = 0.f, ssq1 = 0.f, dot1 = 0.f;
    const float* lg0b = langn + (size_t)tidn0 * 128;
    const float* lg1b = langn + (size_t)tidn1 * 128;
#pragma unroll
    for (int mt = 0; mt < 4; ++mt)
#pragma unroll
      for (int q = 0; q < 4; ++q) {
        int c0 = mt * 32 + q * 8 + 4 * hi;
        float4 lg0 = *(const float4*)(lg0b + c0);
        float4 lg1 = *(const float4*)(lg1b + c0);
        float a0 = acc0[mt][4 * q + 0], a1 = acc0[mt][4 * q + 1];
        float a2 = acc0[mt][4 * q + 2], a3 = acc0[mt][4 * q + 3];
        ssq0 += a0 * a0 + a1 * a1 + a2 * a2 + a3 * a3;
        dot0 += a0 * lg0.x + a1 * lg0.y + a2 * lg0.z + a3 * lg0.w;
        float b0 = acc1[mt][4 * q + 0], b1v = acc1[mt][4 * q + 1];
        float b2v = acc1[mt][4 * q + 2], b3v = acc1[mt][4 * q + 3];
        ssq1 += b0 * b0 + b1v * b1v + b2v * b2v + b3v * b3v;
        dot1 += b0 * lg1.x + b1v * lg1.y + b2v * lg1.z + b3v * lg1.w;
      }
    ssq0 += __shfl_xor(ssq0, 32); dot0 += __shfl_xor(dot0, 32);
    ssq1 += __shfl_xor(ssq1, 32); dot1 += __shfl_xor(dot1, 32);
    if (l < 32) {
      float inv0 = rsqrtf(ssq0), inv1 = rsqrtf(ssq1);
      cs_t[(size_t)row0 * NTASK + n] = dot0 * inv0;
      inv_t[(size_t)row0 * NTASK + n] = inv0;
      cs_t[(size_t)(row0 + 32) * NTASK + n] = dot1 * inv1;
      inv_t[(size_t)(row0 + 32) * NTASK + n] = inv1;
    }
  }

  // ---- q store: C-frags -> swizzled LDS (shW reuse) -> coalesced global
  __syncthreads();   // all weight ds_reads complete before overwrite
  {
    char* stg = (char*)shW;
    const int xm = (lr0 & 7) << 4;   // (lr0+32)&7 == lr0&7
#pragma unroll
    for (int mt = 0; mt < 4; ++mt)
#pragma unroll
      for (int qq = 0; qq < 4; ++qq) {
        int c2 = (mt * 32 + qq * 8 + 4 * hi) * 2;
        uint2 p0, p1;
        p0.x = pack2(acc0[mt][4 * qq + 0], acc0[mt][4 * qq + 1]);
        p0.y = pack2(acc0[mt][4 * qq + 2], acc0[mt][4 * qq + 3]);
        p1.x = pack2(acc1[mt][4 * qq + 0], acc1[mt][4 * qq + 1]);
        p1.y = pack2(acc1[mt][4 * qq + 2], acc1[mt][4 * qq + 3]);
        *(uint2*)(stg + lr0 * 256 + (c2 ^ xm)) = p0;
        *(uint2*)(stg + (lr0 + 32) * 256 + (c2 ^ xm)) = p1;
      }
  }
  __syncthreads();
  {
    const char* stg = (const char*)shW;
#pragma unroll
    for (int i = 0; i < 16; ++i) {
      int lr = w * 64 + i * 4 + (l >> 4);
      int cb = (l & 15) * 16;
      uint4 v = *(const uint4*)(stg + lr * 256 + (cb ^ ((lr & 7) << 4)));
      *(uint4*)((char*)q_t + ((size_t)(rg * 512 + lr) * NTASK + n) * 256 + cb) = v;
    }
  }
}

// ---------------- pass 3: per-row combine (1 wave per row) ----------------

__global__ void __launch_bounds__(256)
pass3_kernel(const float* __restrict__ state, const int* __restrict__ task_id,
             const float* __restrict__ prior, const float* __restrict__ cs_t,
             const float* __restrict__ inv_t, const bf16* __restrict__ q_t,
             float* __restrict__ out_rep, float* __restrict__ out_ltp,
             float* __restrict__ out_tgt, float* __restrict__ out_lat) {
  __shared__ float sppiv[4][NTASK];
  int w = threadIdx.x >> 6, l = threadIdx.x & 63;
  size_t row = (size_t)blockIdx.x * 4 + w;

  // softmax(prior) * inv (inv folded so latent uses unnormalized q)
  float pv = (l < NTASK) ? prior[row * NTASK + l] : -INFINITY;
  float iv = (l < NTASK) ? inv_t[row * NTASK + l] : 0.0f;
  float m = pv;
#pragma unroll
  for (int mm = 1; mm < 64; mm <<= 1) m = fmaxf(m, __shfl_xor(m, mm));
  float e = (l < NTASK) ? expf(pv - m) : 0.0f;
  float s = e;
#pragma unroll
  for (int mm = 1; mm < 64; mm <<= 1) s += __shfl_xor(s, mm);
  if (l < NTASK) sppiv[w][l] = (e / s) * iv;

  // log_softmax(cos*10)
  float c = (l < NTASK) ? cs_t[row * NTASK + l] * 10.0f : -1e30f;
  float cm = c;
#pragma unroll
  for (int mm = 1; mm < 64; mm <<= 1) cm = fmaxf(cm, __shfl_xor(cm, mm));
  float ce = (l < NTASK) ? expf(c - cm) : 0.0f;
  float cs = ce;
#pragma unroll
  for (int mm = 1; mm < 64; mm <<= 1) cs += __shfl_xor(cs, mm);
  if (l < NTASK) out_ltp[row * NTASK + l] = c - cm - logf(cs);

  int tg = task_id[row];
  float ivt = __shfl(iv, tg);
  __syncthreads();

  // latent: lane covers cols {2l, 2l+1}; q_t row-major [row][34][128]
  const bf16* qrow = q_t + row * NTASK * 128;
  float lat0 = 0.f, lat1 = 0.f;
#pragma unroll
  for (int n = 0; n < NTASK; ++n) {
    float pw = sppiv[w][n];
    union { unsigned u; __bf16 h[2]; } q;
    q.u = *(const unsigned*)(qrow + n * 128 + 2 * l);
    lat0 += pw * (float)q.h[0];
    lat1 += pw * (float)q.h[1];
  }
  float2 lv = {lat0, lat1};
  *(float2*)(out_lat + row * 128 + 2 * l) = lv;
  *(float2*)(out_rep + row * 384 + 256 + 2 * l) = lv;

  // latent_target = q[tg] * inv[tg]
  union { unsigned u; __bf16 h[2]; } qt;
  qt.u = *(const unsigned*)(qrow + tg * 128 + 2 * l);
  float2 tv = {(float)qt.h[0] * ivt, (float)qt.h[1] * ivt};
  *(float2*)(out_tgt + row * 128 + 2 * l) = tv;

  // state passthrough
  float4 sv = *(const float4*)(state + row * 256 + l * 4);
  *(float4*)(out_rep + row * 384 + l * 4) = sv;
}

// ---------------- launch ----------------

extern "C" void kernel_launch(void* const* d_in, const int* in_sizes, int n_in,
                              void* d_out, int out_size, void* d_ws, size_t ws_size,
                              hipStream_t stream) {
  (void)in_sizes; (void)n_in; (void)out_size; (void)ws_size;
  const float* state = (const float*)d_in[0];
  const int* task_id = (const int*)d_in[1];
  const float* prior = (const float*)d_in[2];
  const float* W1 = (const float*)d_in[3];
  const float* b1 = (const float*)d_in[4];
  const float* W2 = (const float*)d_in[5];
  const float* b2 = (const float*)d_in[6];
  const float* W3 = (const float*)d_in[7];
  const float* b3 = (const float*)d_in[8];
  const float* lang = (const float*)d_in[9];

  char* ws = (char*)d_ws;
  bf16* wstream = (bf16*)(ws + 0);           //   5,013,504 B (34 x 144KB)
  bf16* sf      = (bf16*)(ws + 5013504);     //   8,388,608 B
  float* langn  = (float*)(ws + 13402112);   //      17,408 B
  float* cs_t   = (float*)(ws + 13419520);   //   2,228,224 B [16384][34]
  float* inv_t  = (float*)(ws + 15647744);   //   2,228,224 B [16384][34]
  bf16* q_t     = (bf16*)(ws + 17875968);    // 142,606,336 B [16384][34][128]
                                             // total 160,482,304 B

  float* out = (float*)d_out;
  float* out_rep = out;                 // [B,384]
  float* out_ltp = out + 6291456;       // [B,34]
  float* out_tgt = out + 6848512;       // [B,128]
  float* out_lat = out + 8945664;       // [B,128]

  prep_w_all<<<1190, 256, 0, stream>>>(W1, W2, W3, b1, b2, b3, wstream);
  prep_state_frags<<<2048, 256, 0, stream>>>(state, sf);
  prep_langn<<<NTASK, 128, 0, stream>>>(lang, langn);
  pass1_kernel<<<NTASK * 32, 512, 0, stream>>>(task_id, wstream, sf, langn,
                                               cs_t, inv_t, q_t);
  pass3_kernel<<<4096, 256, 0, stream>>>(state, task_id, prior, cs_t, inv_t, q_t,
                                         out_rep, out_ltp, out_tgt, out_lat);
}